// Round 1
// baseline (628.600 us; speedup 1.0000x reference)
//
#include <hip/hip_runtime.h>
#include <math.h>

#define SIG_THRESHOLD 0.01f
#define PHASE_INT_THR 0.01f

// ---------------- block reduction helpers (blockDim <= 1024) ----------------

__device__ __forceinline__ float waveReduceSum(float v) {
#pragma unroll
    for (int o = 32; o > 0; o >>= 1) v += __shfl_down(v, o, 64);
    return v;
}
__device__ __forceinline__ int waveReduceMin(int v) {
#pragma unroll
    for (int o = 32; o > 0; o >>= 1) v = min(v, __shfl_down(v, o, 64));
    return v;
}
__device__ __forceinline__ int waveReduceMax(int v) {
#pragma unroll
    for (int o = 32; o > 0; o >>= 1) v = max(v, __shfl_down(v, o, 64));
    return v;
}

__device__ __forceinline__ float blockReduceSum(float v, float* lds) {
    __syncthreads();
    v = waveReduceSum(v);
    int lane = threadIdx.x & 63, wave = threadIdx.x >> 6;
    if (lane == 0) lds[wave] = v;
    __syncthreads();
    int nw = (blockDim.x + 63) >> 6;
    float r = (threadIdx.x < nw) ? lds[threadIdx.x] : 0.0f;
    if (threadIdx.x < 64) r = waveReduceSum(r);
    if (threadIdx.x == 0) lds[0] = r;
    __syncthreads();
    return lds[0];
}
__device__ __forceinline__ int blockReduceMin(int v, int* lds) {
    __syncthreads();
    v = waveReduceMin(v);
    int lane = threadIdx.x & 63, wave = threadIdx.x >> 6;
    if (lane == 0) lds[wave] = v;
    __syncthreads();
    int nw = (blockDim.x + 63) >> 6;
    int r = (threadIdx.x < nw) ? lds[threadIdx.x] : 0x7fffffff;
    if (threadIdx.x < 64) r = waveReduceMin(r);
    if (threadIdx.x == 0) lds[0] = r;
    __syncthreads();
    return lds[0];
}
__device__ __forceinline__ int blockReduceMax(int v, int* lds) {
    __syncthreads();
    v = waveReduceMax(v);
    int lane = threadIdx.x & 63, wave = threadIdx.x >> 6;
    if (lane == 0) lds[wave] = v;
    __syncthreads();
    int nw = (blockDim.x + 63) >> 6;
    int r = (threadIdx.x < nw) ? lds[threadIdx.x] : (int)0x80000000;
    if (threadIdx.x < 64) r = waveReduceMax(r);
    if (threadIdx.x == 0) lds[0] = r;
    __syncthreads();
    return lds[0];
}

// ---------------- main per-row kernel ----------------
// One block per row. Each thread owns a contiguous chunk of n/blockDim real
// indices (and the matching imag indices at +n). Single pass over all data,
// plus a tiny cached re-read for the <=2 chunks straddling the significance
// bounds per component.

__global__ void __launch_bounds__(512)
prl_row_kernel(const float* __restrict__ pred, const float* __restrict__ label,
               float* __restrict__ row_out, int n, int two_n) {
    __shared__ float s_f[16];
    __shared__ int s_i[16];

    const int row = blockIdx.x;
    const float* __restrict__ P = pred  + (size_t)row * two_n;
    const float* __restrict__ L = label + (size_t)row * two_n;

    const int tid = threadIdx.x;
    const int chunk = n / blockDim.x;     // 32768 / 512 = 64
    const int c0 = tid * chunk;
    const int c1 = c0 + chunk;

    const float4* __restrict__ lr4 = reinterpret_cast<const float4*>(L + c0);
    const float4* __restrict__ li4 = reinterpret_cast<const float4*>(L + n + c0);
    const float4* __restrict__ pr4 = reinterpret_cast<const float4*>(P + c0);
    const float4* __restrict__ pi4 = reinterpret_cast<const float4*>(P + n + c0);

    float sum_r = 0.f, sum_i = 0.f, sum_int = 0.f, sum_ph = 0.f;
    int cfr = n, clr = -1, cfi = n, cli = -1;

    const int nv = chunk / 4;
    for (int j = 0; j < nv; ++j) {
        float4 lrv = lr4[j];
        float4 liv = li4[j];
        float4 prv = pr4[j];
        float4 piv = pi4[j];
#pragma unroll
        for (int k = 0; k < 4; ++k) {
            float lrk = (&lrv.x)[k], lik = (&liv.x)[k];
            float prk = (&prv.x)[k], pik = (&piv.x)[k];
            int idx = c0 + 4 * j + k;

            float dr = prk - lrk;  sum_r += dr * dr;
            float di = pik - lik;  sum_i += di * di;

            float lint = lrk * lrk + lik * lik;
            float pint = prk * prk + pik * pik;
            float dint = pint - lint;  sum_int += dint * dint;

            float dph = atan2f(pik, prk) - atan2f(lik, lrk);
            sum_ph += (lint >= PHASE_INT_THR) ? dph * dph : 0.0f;

            if (fabsf(lrk) > SIG_THRESHOLD) { if (idx < cfr) cfr = idx; clr = idx; }
            if (fabsf(lik) > SIG_THRESHOLD) { if (idx < cfi) cfi = idx; cli = idx; }
        }
    }

    // block totals
    float tot_r   = blockReduceSum(sum_r, s_f);
    float tot_i   = blockReduceSum(sum_i, s_f);
    float tot_int = blockReduceSum(sum_int, s_f);
    float tot_ph  = blockReduceSum(sum_ph, s_f);

    int fr = blockReduceMin(cfr, s_i);
    int lr = blockReduceMax(clr, s_i);
    int fi = blockReduceMin(cfi, s_i);
    int li = blockReduceMax(cli, s_i);
    if (fr == n) { fr = 0; lr = n - 1; }   // no significant element: scale all 1
    if (fi == n) { fi = 0; li = n - 1; }

    // outside-of-bounds extra contribution (scale 2.0 = base + extra)
    float o_r;
    if (c1 <= fr || c0 > lr) {
        o_r = sum_r;                        // chunk fully outside
    } else if (c0 >= fr && (c1 - 1) <= lr) {
        o_r = 0.f;                          // chunk fully inside
    } else {                                // straddles a bound: re-read (cached)
        o_r = 0.f;
        for (int i = c0; i < c1; ++i) {
            if (i < fr || i > lr) { float d = P[i] - L[i]; o_r += d * d; }
        }
    }
    float o_i;
    if (c1 <= fi || c0 > li) {
        o_i = sum_i;
    } else if (c0 >= fi && (c1 - 1) <= li) {
        o_i = 0.f;
    } else {
        o_i = 0.f;
        for (int i = c0; i < c1; ++i) {
            if (i < fi || i > li) { float d = P[n + i] - L[n + i]; o_i += d * d; }
        }
    }

    float tot_or = blockReduceSum(o_r, s_f);
    float tot_oi = blockReduceSum(o_i, s_f);

    if (tid == 0) {
        float wr = tot_r + tot_or;
        float wi = tot_i + tot_oi;
        float per_sample = (wr + wi + 10.0f * tot_int + 5.0f * tot_ph) / (float)n;
        row_out[row] = per_sample;
    }
}

// ---------------- finalize: mean over rows ----------------
__global__ void __launch_bounds__(1024)
prl_finalize_kernel(const float* __restrict__ rows, float* __restrict__ out, int B) {
    __shared__ float s_f[16];
    float v = 0.f;
    for (int i = threadIdx.x; i < B; i += blockDim.x) v += rows[i];
    float t = blockReduceSum(v, s_f);
    if (threadIdx.x == 0) out[0] = t / (float)B;
}

extern "C" void kernel_launch(void* const* d_in, const int* in_sizes, int n_in,
                              void* d_out, int out_size, void* d_ws, size_t ws_size,
                              hipStream_t stream) {
    const float* pred  = (const float*)d_in[0];
    const float* label = (const float*)d_in[1];
    // spectrogram (d_in[2]) is unused by the reference.

    const int B     = in_sizes[2] / (128 * 128);   // 1024
    const int two_n = in_sizes[0] / B;             // 65536
    const int n     = two_n / 2;                   // 32768

    float* row_out = (float*)d_ws;                 // B floats of scratch
    float* out     = (float*)d_out;

    prl_row_kernel<<<B, 512, 0, stream>>>(pred, label, row_out, n, two_n);
    prl_finalize_kernel<<<1, 1024, 0, stream>>>(row_out, out, B);
}

// Round 2
// 117.577 us; speedup vs baseline: 5.3463x; 5.3463x over previous
//
#include <hip/hip_runtime.h>
#include <math.h>

#define SIG_THRESHOLD 0.01f
#define PHASE_INT_THR 0.01f

// ---------------- block reduction helpers ----------------

__device__ __forceinline__ float waveReduceSum(float v) {
#pragma unroll
    for (int o = 32; o > 0; o >>= 1) v += __shfl_down(v, o, 64);
    return v;
}
__device__ __forceinline__ int waveReduceMin(int v) {
#pragma unroll
    for (int o = 32; o > 0; o >>= 1) v = min(v, __shfl_down(v, o, 64));
    return v;
}
__device__ __forceinline__ int waveReduceMax(int v) {
#pragma unroll
    for (int o = 32; o > 0; o >>= 1) v = max(v, __shfl_down(v, o, 64));
    return v;
}

__device__ __forceinline__ float blockReduceSum(float v, float* lds) {
    __syncthreads();
    v = waveReduceSum(v);
    int lane = threadIdx.x & 63, wave = threadIdx.x >> 6;
    if (lane == 0) lds[wave] = v;
    __syncthreads();
    int nw = (blockDim.x + 63) >> 6;
    float r = (threadIdx.x < nw) ? lds[threadIdx.x] : 0.0f;
    if (threadIdx.x < 64) r = waveReduceSum(r);
    if (threadIdx.x == 0) lds[0] = r;
    __syncthreads();
    return lds[0];
}
__device__ __forceinline__ int blockReduceMin(int v, int* lds) {
    __syncthreads();
    v = waveReduceMin(v);
    int lane = threadIdx.x & 63, wave = threadIdx.x >> 6;
    if (lane == 0) lds[wave] = v;
    __syncthreads();
    int nw = (blockDim.x + 63) >> 6;
    int r = (threadIdx.x < nw) ? lds[threadIdx.x] : 0x7fffffff;
    if (threadIdx.x < 64) r = waveReduceMin(r);
    if (threadIdx.x == 0) lds[0] = r;
    __syncthreads();
    return lds[0];
}
__device__ __forceinline__ int blockReduceMax(int v, int* lds) {
    __syncthreads();
    v = waveReduceMax(v);
    int lane = threadIdx.x & 63, wave = threadIdx.x >> 6;
    if (lane == 0) lds[wave] = v;
    __syncthreads();
    int nw = (blockDim.x + 63) >> 6;
    int r = (threadIdx.x < nw) ? lds[threadIdx.x] : (int)0x80000000;
    if (threadIdx.x < 64) r = waveReduceMax(r);
    if (threadIdx.x == 0) lds[0] = r;
    __syncthreads();
    return lds[0];
}

// ---------------- main per-row kernel ----------------
// One block per row. Phase 1: fully-coalesced float4 interleaved pass
// (lane t reads float4 #(w*blockDim+t); consecutive lanes -> consecutive 16B).
// Block-reduce sums + significance bounds. Phase 2: the penalty region is two
// contiguous spans [0,fr) and (lr,n) (expected ~empty for this data); re-read
// them coalesced for the extra 1x contribution (scale 2.0 = base + extra).

__global__ void __launch_bounds__(512)
prl_row_kernel(const float* __restrict__ pred, const float* __restrict__ label,
               float* __restrict__ row_out, int n, int two_n) {
    __shared__ float s_f[16];
    __shared__ int s_i[16];

    const int row = blockIdx.x;
    const float* __restrict__ P = pred  + (size_t)row * two_n;
    const float* __restrict__ L = label + (size_t)row * two_n;

    const int tid = threadIdx.x;
    const int nt  = blockDim.x;

    const float4* __restrict__ Lr4 = reinterpret_cast<const float4*>(L);
    const float4* __restrict__ Li4 = reinterpret_cast<const float4*>(L + n);
    const float4* __restrict__ Pr4 = reinterpret_cast<const float4*>(P);
    const float4* __restrict__ Pi4 = reinterpret_cast<const float4*>(P + n);

    float sum_r = 0.f, sum_i = 0.f, sum_int = 0.f, sum_ph = 0.f;
    int cfr = n, clr = -1, cfi = n, cli = -1;

    const int nvec = n / 4;                 // float4s per half-row
    for (int v = tid; v < nvec; v += nt) {
        float4 lrv = Lr4[v];
        float4 liv = Li4[v];
        float4 prv = Pr4[v];
        float4 piv = Pi4[v];
        const int idx0 = v * 4;
#pragma unroll
        for (int k = 0; k < 4; ++k) {
            float lrk = (&lrv.x)[k], lik = (&liv.x)[k];
            float prk = (&prv.x)[k], pik = (&piv.x)[k];
            int idx = idx0 + k;

            float dr = prk - lrk;  sum_r += dr * dr;
            float di = pik - lik;  sum_i += di * di;

            float lint = lrk * lrk + lik * lik;
            float pint = prk * prk + pik * pik;
            float dint = pint - lint;  sum_int += dint * dint;

            float dph = atan2f(pik, prk) - atan2f(lik, lrk);
            sum_ph += (lint >= PHASE_INT_THR) ? dph * dph : 0.0f;

            if (fabsf(lrk) > SIG_THRESHOLD) { if (idx < cfr) cfr = idx; if (idx > clr) clr = idx; }
            if (fabsf(lik) > SIG_THRESHOLD) { if (idx < cfi) cfi = idx; if (idx > cli) cli = idx; }
        }
    }

    // block totals
    float tot_r   = blockReduceSum(sum_r, s_f);
    float tot_i   = blockReduceSum(sum_i, s_f);
    float tot_int = blockReduceSum(sum_int, s_f);
    float tot_ph  = blockReduceSum(sum_ph, s_f);

    int fr = blockReduceMin(cfr, s_i);
    int lr = blockReduceMax(clr, s_i);
    int fi = blockReduceMin(cfi, s_i);
    int li = blockReduceMax(cli, s_i);
    if (fr == n) { fr = 0; lr = n - 1; }   // no significant element: scale 1 everywhere
    if (fi == n) { fi = 0; li = n - 1; }

    // Phase 2: extra 1x contribution for the two outside spans, coalesced.
    float o_r = 0.f, o_i = 0.f;
    for (int i = tid; i < fr; i += nt)          { float d = P[i] - L[i];         o_r += d * d; }
    for (int i = lr + 1 + tid; i < n; i += nt)  { float d = P[i] - L[i];         o_r += d * d; }
    for (int i = tid; i < fi; i += nt)          { float d = P[n + i] - L[n + i]; o_i += d * d; }
    for (int i = li + 1 + tid; i < n; i += nt)  { float d = P[n + i] - L[n + i]; o_i += d * d; }

    float tot_or = blockReduceSum(o_r, s_f);
    float tot_oi = blockReduceSum(o_i, s_f);

    if (tid == 0) {
        float wr = tot_r + tot_or;
        float wi = tot_i + tot_oi;
        float per_sample = (wr + wi + 10.0f * tot_int + 5.0f * tot_ph) / (float)n;
        row_out[row] = per_sample;
    }
}

// ---------------- finalize: mean over rows ----------------
__global__ void __launch_bounds__(1024)
prl_finalize_kernel(const float* __restrict__ rows, float* __restrict__ out, int B) {
    __shared__ float s_f[16];
    float v = 0.f;
    for (int i = threadIdx.x; i < B; i += blockDim.x) v += rows[i];
    float t = blockReduceSum(v, s_f);
    if (threadIdx.x == 0) out[0] = t / (float)B;
}

extern "C" void kernel_launch(void* const* d_in, const int* in_sizes, int n_in,
                              void* d_out, int out_size, void* d_ws, size_t ws_size,
                              hipStream_t stream) {
    const float* pred  = (const float*)d_in[0];
    const float* label = (const float*)d_in[1];
    // spectrogram (d_in[2]) is unused by the reference.

    const int B     = in_sizes[2] / (128 * 128);   // 1024
    const int two_n = in_sizes[0] / B;             // 65536
    const int n     = two_n / 2;                   // 32768

    float* row_out = (float*)d_ws;                 // B floats of scratch
    float* out     = (float*)d_out;

    prl_row_kernel<<<B, 512, 0, stream>>>(pred, label, row_out, n, two_n);
    prl_finalize_kernel<<<1, 1024, 0, stream>>>(row_out, out, B);
}

// Round 3
// 113.538 us; speedup vs baseline: 5.5365x; 1.0356x over previous
//
#include <hip/hip_runtime.h>
#include <math.h>

#define SIG_THRESHOLD 0.01f
#define PHASE_INT_THR 0.01f

// ---------------- fast atan2 ----------------
// Range-reduce to t = min/max in [0,1], degree-11 odd minimax for atan(t),
// then quadrant fixup + copysign. Max error ~1e-6 rad — final-scalar impact
// ~1e-3 vs 2.33 threshold. ~18 VALU ops + 1 v_rcp vs ~50+ for libm atan2f.
__device__ __forceinline__ float fast_atan2f(float y, float x) {
    float ax = fabsf(x), ay = fabsf(y);
    float mx = fmaxf(ax, ay), mn = fminf(ax, ay);
    float t = mn * __builtin_amdgcn_rcpf(mx);
    t = (mx == 0.0f) ? 0.0f : t;          // atan2(0,0) -> 0
    float s = t * t;
    float p =        -0.01172120f;
    p = fmaf(s, p,    0.05265332f);
    p = fmaf(s, p,   -0.11643287f);
    p = fmaf(s, p,    0.19354346f);
    p = fmaf(s, p,   -0.33262347f);
    p = fmaf(s, p,    0.99997726f);
    float r = p * t;                       // atan(mn/mx) in [0, pi/4]
    r = (ay > ax) ? (1.57079632679f - r) : r;
    r = (x < 0.0f) ? (3.14159265359f - r) : r;
    return copysignf(r, y);
}

// ---------------- block reduction helpers ----------------

__device__ __forceinline__ float waveReduceSum(float v) {
#pragma unroll
    for (int o = 32; o > 0; o >>= 1) v += __shfl_down(v, o, 64);
    return v;
}
__device__ __forceinline__ int waveReduceMin(int v) {
#pragma unroll
    for (int o = 32; o > 0; o >>= 1) v = min(v, __shfl_down(v, o, 64));
    return v;
}
__device__ __forceinline__ int waveReduceMax(int v) {
#pragma unroll
    for (int o = 32; o > 0; o >>= 1) v = max(v, __shfl_down(v, o, 64));
    return v;
}

__device__ __forceinline__ float blockReduceSum(float v, float* lds) {
    __syncthreads();
    v = waveReduceSum(v);
    int lane = threadIdx.x & 63, wave = threadIdx.x >> 6;
    if (lane == 0) lds[wave] = v;
    __syncthreads();
    int nw = (blockDim.x + 63) >> 6;
    float r = (threadIdx.x < nw) ? lds[threadIdx.x] : 0.0f;
    if (threadIdx.x < 64) r = waveReduceSum(r);
    if (threadIdx.x == 0) lds[0] = r;
    __syncthreads();
    return lds[0];
}
__device__ __forceinline__ int blockReduceMin(int v, int* lds) {
    __syncthreads();
    v = waveReduceMin(v);
    int lane = threadIdx.x & 63, wave = threadIdx.x >> 6;
    if (lane == 0) lds[wave] = v;
    __syncthreads();
    int nw = (blockDim.x + 63) >> 6;
    int r = (threadIdx.x < nw) ? lds[threadIdx.x] : 0x7fffffff;
    if (threadIdx.x < 64) r = waveReduceMin(r);
    if (threadIdx.x == 0) lds[0] = r;
    __syncthreads();
    return lds[0];
}
__device__ __forceinline__ int blockReduceMax(int v, int* lds) {
    __syncthreads();
    v = waveReduceMax(v);
    int lane = threadIdx.x & 63, wave = threadIdx.x >> 6;
    if (lane == 0) lds[wave] = v;
    __syncthreads();
    int nw = (blockDim.x + 63) >> 6;
    int r = (threadIdx.x < nw) ? lds[threadIdx.x] : (int)0x80000000;
    if (threadIdx.x < 64) r = waveReduceMax(r);
    if (threadIdx.x == 0) lds[0] = r;
    __syncthreads();
    return lds[0];
}

// ---------------- per-element body ----------------
__device__ __forceinline__ void process4(float4 lrv, float4 liv, float4 prv, float4 piv,
                                         int idx0,
                                         float& sum_r, float& sum_i, float& sum_int, float& sum_ph,
                                         int& cfr, int& clr, int& cfi, int& cli) {
#pragma unroll
    for (int k = 0; k < 4; ++k) {
        float lrk = (&lrv.x)[k], lik = (&liv.x)[k];
        float prk = (&prv.x)[k], pik = (&piv.x)[k];
        int idx = idx0 + k;

        float dr = prk - lrk;  sum_r += dr * dr;
        float di = pik - lik;  sum_i += di * di;

        float lint = fmaf(lrk, lrk, lik * lik);
        float pint = fmaf(prk, prk, pik * pik);
        float dint = pint - lint;  sum_int += dint * dint;

        float dph = fast_atan2f(pik, prk) - fast_atan2f(lik, lrk);
        sum_ph += (lint >= PHASE_INT_THR) ? dph * dph : 0.0f;

        bool sr = fabsf(lrk) > SIG_THRESHOLD;
        bool si = fabsf(lik) > SIG_THRESHOLD;
        cfr = (sr && idx < cfr) ? idx : cfr;
        clr = sr ? idx : clr;                 // idx monotone per thread
        cfi = (si && idx < cfi) ? idx : cfi;
        cli = si ? idx : cli;
    }
}

// ---------------- main per-row kernel ----------------
__global__ void __launch_bounds__(512)
prl_row_kernel(const float* __restrict__ pred, const float* __restrict__ label,
               float* __restrict__ row_out, int n, int two_n) {
    __shared__ float s_f[16];
    __shared__ int s_i[16];

    const int row = blockIdx.x;
    const float* __restrict__ P = pred  + (size_t)row * two_n;
    const float* __restrict__ L = label + (size_t)row * two_n;

    const int tid = threadIdx.x;
    const int nt  = blockDim.x;

    const float4* __restrict__ Lr4 = reinterpret_cast<const float4*>(L);
    const float4* __restrict__ Li4 = reinterpret_cast<const float4*>(L + n);
    const float4* __restrict__ Pr4 = reinterpret_cast<const float4*>(P);
    const float4* __restrict__ Pi4 = reinterpret_cast<const float4*>(P + n);

    float sum_r = 0.f, sum_i = 0.f, sum_int = 0.f, sum_ph = 0.f;
    int cfr = n, clr = -1, cfi = n, cli = -1;

    const int nvec = n / 4;                 // 8192 float4s per half-row
    // unroll x2: two independent float4-quads in flight per thread
    for (int v = tid; v < nvec; v += 2 * nt) {
        const int v1 = v + nt;
        float4 a0 = Lr4[v],  b0 = Li4[v],  c0 = Pr4[v],  d0 = Pi4[v];
        float4 a1, b1, c1, d1;
        const bool h1 = v1 < nvec;
        if (h1) { a1 = Lr4[v1]; b1 = Li4[v1]; c1 = Pr4[v1]; d1 = Pi4[v1]; }
        process4(a0, b0, c0, d0, v * 4, sum_r, sum_i, sum_int, sum_ph, cfr, clr, cfi, cli);
        if (h1)
            process4(a1, b1, c1, d1, v1 * 4, sum_r, sum_i, sum_int, sum_ph, cfr, clr, cfi, cli);
    }

    // block totals
    float tot_r   = blockReduceSum(sum_r, s_f);
    float tot_i   = blockReduceSum(sum_i, s_f);
    float tot_int = blockReduceSum(sum_int, s_f);
    float tot_ph  = blockReduceSum(sum_ph, s_f);

    int fr = blockReduceMin(cfr, s_i);
    int lr = blockReduceMax(clr, s_i);
    int fi = blockReduceMin(cfi, s_i);
    int li = blockReduceMax(cli, s_i);
    if (fr == n) { fr = 0; lr = n - 1; }   // no significant element: scale 1 everywhere
    if (fi == n) { fi = 0; li = n - 1; }

    // Phase 2: extra 1x contribution for the two outside spans (usually empty).
    float o_r = 0.f, o_i = 0.f;
    for (int i = tid; i < fr; i += nt)          { float d = P[i] - L[i];         o_r += d * d; }
    for (int i = lr + 1 + tid; i < n; i += nt)  { float d = P[i] - L[i];         o_r += d * d; }
    for (int i = tid; i < fi; i += nt)          { float d = P[n + i] - L[n + i]; o_i += d * d; }
    for (int i = li + 1 + tid; i < n; i += nt)  { float d = P[n + i] - L[n + i]; o_i += d * d; }

    float tot_or = blockReduceSum(o_r, s_f);
    float tot_oi = blockReduceSum(o_i, s_f);

    if (tid == 0) {
        float wr = tot_r + tot_or;
        float wi = tot_i + tot_oi;
        float per_sample = (wr + wi + 10.0f * tot_int + 5.0f * tot_ph) / (float)n;
        row_out[row] = per_sample;
    }
}

// ---------------- finalize: mean over rows ----------------
__global__ void __launch_bounds__(1024)
prl_finalize_kernel(const float* __restrict__ rows, float* __restrict__ out, int B) {
    __shared__ float s_f[16];
    float v = 0.f;
    for (int i = threadIdx.x; i < B; i += blockDim.x) v += rows[i];
    float t = blockReduceSum(v, s_f);
    if (threadIdx.x == 0) out[0] = t / (float)B;
}

extern "C" void kernel_launch(void* const* d_in, const int* in_sizes, int n_in,
                              void* d_out, int out_size, void* d_ws, size_t ws_size,
                              hipStream_t stream) {
    const float* pred  = (const float*)d_in[0];
    const float* label = (const float*)d_in[1];
    // spectrogram (d_in[2]) is unused by the reference.

    const int B     = in_sizes[2] / (128 * 128);   // 1024
    const int two_n = in_sizes[0] / B;             // 65536
    const int n     = two_n / 2;                   // 32768

    float* row_out = (float*)d_ws;                 // B floats of scratch
    float* out     = (float*)d_out;

    prl_row_kernel<<<B, 512, 0, stream>>>(pred, label, row_out, n, two_n);
    prl_finalize_kernel<<<1, 1024, 0, stream>>>(row_out, out, B);
}